// Round 10
// baseline (873.168 us; speedup 1.0000x reference)
//
#include <hip/hip_runtime.h>
#include <hip/hip_cooperative_groups.h>

namespace cg = cooperative_groups;

#define NN 10000
#define NE 400000
#define HD 128
#define NIN 6
#define EDIM 3
#define NL 4
#define CAP 96
#define LN_EPS 1e-5f
#define GRID_C 625
#define NTHR 512
#define TOTTHR (GRID_C * NTHR)

typedef unsigned short u16;
using short8 = __attribute__((ext_vector_type(8))) short;
using f32x4 = __attribute__((ext_vector_type(4))) float;

__device__ __forceinline__ u16 f2bf(float x) {
    unsigned u = __float_as_uint(x);
    return (u16)((u + 0x7fff + ((u >> 16) & 1)) >> 16);
}
__device__ __forceinline__ float bf2f(u16 h) { return __uint_as_float(((unsigned)h) << 16); }
__device__ __forceinline__ void split2(float x, u16& hi, u16& lo) {
    hi = f2bf(x);
    lo = f2bf(x - bf2f(hi));
}
#define MFMA(a, b, c) __builtin_amdgcn_mfma_f32_16x16x32_bf16((a), (b), (c), 0, 0, 0)

// ================= shared device bodies =================

// Phase-A work item: M2/c2/cnt-zero/fG2/fPQ/fDec/fEnc  (idx < 104720)
__device__ __forceinline__ void prep_item(
    int idx, const float* msg_w2, const float* msg_b2, const float* upd_w1, const float* upd_w2,
    const float* msg_w1, const float* dec_w1, const float* enc_w2, float* M2, float* c2, int* cnt,
    u16* fG2, u16* fPQ, u16* fDec, u16* fEnc) {
    if (idx < 65536) {
        int l = idx >> 14, rem = idx & 16383, i = rem >> 7, jj = rem & 127;
        const float* U1b = upd_w1 + (size_t)l * 2 * HD * HD + (size_t)HD * HD;
        const float* W2 = msg_w2 + (size_t)l * HD * HD + (size_t)i * HD;
        float acc = 0.f;
        for (int t = 0; t < HD; ++t) acc += W2[t] * U1b[(size_t)t * HD + jj];
        M2[idx] = acc;
    } else if (idx < 66048) {
        int r = idx - 65536;
        int l = r >> 7, jj = r & 127;
        const float* U1b = upd_w1 + (size_t)l * 2 * HD * HD + (size_t)HD * HD;
        const float* b2 = msg_b2 + l * HD;
        float acc = 0.f;
        for (int t = 0; t < HD; ++t) acc += b2[t] * U1b[(size_t)t * HD + jj];
        c2[r] = acc;
    } else if (idx < 76048) {
        cnt[idx - 66048] = 0;
    } else if (idx < 84240) {
        int gg = idx - 76048;
        int l = gg >> 11, r = gg & 2047;
        int ct = r >> 8, ks = (r >> 6) & 3, ln = r & 63;
        int n = ct * 16 + (ln & 15), kb = ks * 32 + ((ln >> 4) << 3);
        u16* dst = fG2 + (size_t)gg * 8;
        const float* W = upd_w2 + (size_t)l * 128 * 128;
#pragma unroll
        for (int j = 0; j < 8; ++j) dst[j] = f2bf(W[(size_t)(kb + j) * 128 + n]);
    } else if (idx < 100624) {
        int gg = idx - 84240;
        int li = gg >> 12, r = gg & 4095;
        int ct = r >> 8, ks = (r >> 6) & 3, ln = r & 63;
        int n = ct * 16 + (ln & 15), kb = ks * 32 + ((ln >> 4) << 3);
        u16* dst = fPQ + (size_t)gg * 8;
        const float* W = msg_w1 + (size_t)li * (2 * HD + EDIM) * HD;
#pragma unroll
        for (int j = 0; j < 8; ++j) {
            int k = kb + j;
            float v = (n < 128) ? W[(size_t)k * 128 + n] : W[(size_t)(128 + k) * 128 + (n - 128)];
            dst[j] = f2bf(v);
        }
    } else if (idx < 102672) {
        int r = idx - 100624;
        int ct = r >> 8, ks = (r >> 6) & 3, ln = r & 63;
        int n = ct * 16 + (ln & 15), kb = ks * 32 + ((ln >> 4) << 3);
        u16* dst = fDec + (size_t)r * 8;
#pragma unroll
        for (int j = 0; j < 8; ++j) dst[j] = f2bf(dec_w1[(size_t)(kb + j) * 128 + n]);
    } else if (idx < 104720) {
        int r = idx - 102672;
        int ct = r >> 8, ks = (r >> 6) & 3, ln = r & 63;
        int n = ct * 16 + (ln & 15), kb = ks * 32 + ((ln >> 4) << 3);
        u16* dst = fEnc + (size_t)r * 8;
#pragma unroll
        for (int j = 0; j < 8; ++j) dst[j] = f2bf(enc_w2[(size_t)(kb + j) * 128 + n]);
    }
}

__device__ __forceinline__ void fg1_item(int g, const float* upd_w1, const float* M2, u16* fG1) {
    int l = g >> 12, r = g & 4095;
    int ct = r >> 9, ks = (r >> 6) & 7, ln = r & 63;
    int n = ct * 16 + (ln & 15), kb = ks * 32 + ((ln >> 4) << 3);
    u16* dst = fG1 + (size_t)g * 8;
    const float* U = upd_w1 + (size_t)l * 256 * 128;
    const float* Ml = M2 + (size_t)l * 128 * 128;
#pragma unroll
    for (int j = 0; j < 8; ++j) {
        int k = kb + j;
        float v = (k < 128) ? U[(size_t)k * 128 + n] : Ml[(size_t)(k - 128) * 128 + n];
        dst[j] = f2bf(v);
    }
}

// encoder body for one 16-node band (512 threads)
__device__ __forceinline__ void enc_body(
    int band, int tid, const float* x, const float* ew1, const float* eb1, const u16* fEnc,
    const float* eb2, const u16* fPQ0, const float* mb1, u16* h_hi, u16* h_lo, float* PQf, u16* Qb,
    u16* tHi, u16* tLo) {
    int w = tid >> 6, lane = tid & 63, q = lane >> 4, c = lane & 15;
    {
        int col = w * 16 + c;
        float wv[NIN];
#pragma unroll
        for (int k = 0; k < NIN; ++k) wv[k] = ew1[k * HD + col];
        float ebv = eb1[col];
#pragma unroll
        for (int reg = 0; reg < 4; ++reg) {
            int row = band + q * 4 + reg;
            float t = ebv;
#pragma unroll
            for (int k = 0; k < NIN; ++k) t += x[(size_t)row * NIN + k] * wv[k];
            t = fmaxf(t, 0.f);
            u16 hi, lo;
            split2(t, hi, lo);
            int r16 = q * 4 + reg;
            int a = r16 * 128 + (((col >> 3) ^ r16) << 3) + (col & 7);
            tHi[a] = hi;
            tLo[a] = lo;
        }
    }
    __syncthreads();
    short8 aH[4], aL[4];
#pragma unroll
    for (int ks = 0; ks < 4; ++ks) {
        int a = c * 128 + (((ks * 4 + q) ^ c) << 3);
        aH[ks] = *(const short8*)&tHi[a];
        aL[ks] = *(const short8*)&tLo[a];
    }
    f32x4 acc = {0, 0, 0, 0};
    {
        const u16* fb = fEnc + (size_t)w * 4 * 512 + lane * 8;
#pragma unroll
        for (int ks = 0; ks < 4; ++ks) {
            short8 b = *(const short8*)(fb + ks * 512);
            acc = MFMA(aH[ks], b, acc);
            acc = MFMA(aL[ks], b, acc);
        }
    }
    __syncthreads();
    {
        int col = w * 16 + c;
        float ebv = eb2[col];
#pragma unroll
        for (int reg = 0; reg < 4; ++reg) {
            int r16 = q * 4 + reg, row = band + r16;
            float hval = acc[reg] + ebv;
            u16 hi, lo;
            split2(hval, hi, lo);
            h_hi[(size_t)row * HD + col] = hi;
            h_lo[(size_t)row * HD + col] = lo;
            int a = r16 * 128 + (((col >> 3) ^ r16) << 3) + (col & 7);
            tHi[a] = hi;
            tLo[a] = lo;
        }
    }
    __syncthreads();
#pragma unroll
    for (int ks = 0; ks < 4; ++ks) {
        int a = c * 128 + (((ks * 4 + q) ^ c) << 3);
        aH[ks] = *(const short8*)&tHi[a];
        aL[ks] = *(const short8*)&tLo[a];
    }
#pragma unroll
    for (int i = 0; i < 2; ++i) {
        int ctg = w * 2 + i;
        const u16* fb = fPQ0 + (size_t)ctg * 4 * 512 + lane * 8;
        f32x4 a3 = {0, 0, 0, 0};
#pragma unroll
        for (int ks = 0; ks < 4; ++ks) {
            short8 b = *(const short8*)(fb + ks * 512);
            a3 = MFMA(aH[ks], b, a3);
            a3 = MFMA(aL[ks], b, a3);
        }
        int col = ctg * 16 + c;
        if (ctg < 8) {
            float bias = mb1[col];
#pragma unroll
            for (int reg = 0; reg < 4; ++reg)
                PQf[(size_t)(band + q * 4 + reg) * HD + col] = a3[reg] + bias;
        } else {
            int colq = col - 128;
#pragma unroll
            for (int reg = 0; reg < 4; ++reg)
                Qb[(size_t)(band + q * 4 + reg) * HD + colq] = f2bf(a3[reg]);
        }
    }
}

// fused layer body for one 16-node band (512 threads) — R6 edge phase, hoisted h-frags
__device__ __forceinline__ void layer_body(
    int band, int tid, bool LAST, const float* PQin, const u16* Qin, const int* cnt,
    const float4* sea, const float* wc, u16* h_hi, u16* h_lo, const u16* fG1l, const u16* fG2l,
    const float* ub1, const float* c2l, const float* ub2, const float* g, const float* bb,
    const u16* fPQn, const float* nb1, float* PQout, u16* Qout, const u16* fDec, const float* db1,
    const float* dw2, const float* db2, float* out, u16* sHi, u16* sLo, u16* tHi, u16* tLo,
    float (*red)[8][2]) {
    int w = tid >> 6, lane = tid & 63, q = lane >> 4, c = lane & 15;
    int j = lane * 2;
    // edge phase: wave w handles rows {2w, 2w+1}
    {
        float2 wcr0 = *(const float2*)(wc + j);
        float2 wcr1 = *(const float2*)(wc + HD + j);
        float2 wcr2 = *(const float2*)(wc + 2 * HD + j);
#pragma unroll
        for (int i = 0; i < 2; ++i) {
            int r16 = w * 2 + i;
            int n = __builtin_amdgcn_readfirstlane(band + r16);
            int cn = cnt[n];
            float invn = 1.0f / fmaxf((float)cn, 1.0f);
            int cle = __builtin_amdgcn_readfirstlane(cn < CAP ? cn : CAP);
            float2 p = *(const float2*)(PQin + (size_t)n * HD + j);
            float acc0 = 0.f, acc1 = 0.f;
            const float4* bucket = sea + (size_t)n * CAP;
            auto edge1 = [&](float4 Av) {
                int sv = (int)__float_as_uint(Av.w);
                float c0 = Av.x * wcr0.x + Av.y * wcr1.x + Av.z * wcr2.x;
                float c1 = Av.x * wcr0.y + Av.y * wcr1.y + Av.z * wcr2.y;
                unsigned u = *(const unsigned*)(Qin + (size_t)sv * HD + j);
                acc0 += fmaxf(p.x + __uint_as_float(u << 16) + c0, 0.f);
                acc1 += fmaxf(p.y + __uint_as_float(u & 0xffff0000u) + c1, 0.f);
            };
            int e = 0;
            for (; e + 3 < cle; e += 4) {
                float4 A0 = bucket[e], A1 = bucket[e + 1], A2 = bucket[e + 2], A3 = bucket[e + 3];
                edge1(A0);
                edge1(A1);
                edge1(A2);
                edge1(A3);
            }
            for (; e < cle; ++e) edge1(bucket[e]);
            float v0 = acc0 * invn, v1 = acc1 * invn;
            u16 h0, l0, h1, l1;
            split2(v0, h0, l0);
            split2(v1, h1, l1);
            int a = r16 * 128 + (((j >> 3) ^ r16) << 3) + (j & 7);
            *(ushort2*)&sHi[a] = make_ushort2(h0, h1);
            *(ushort2*)&sLo[a] = make_ushort2(l0, l1);
        }
    }
    __syncthreads();
    // G1: hoisted global h-frags; LDS S-frags in-loop
    f32x4 acc = {0, 0, 0, 0};
    {
        const u16* fb = fG1l + (size_t)w * 8 * 512 + lane * 8;
        size_t rb = (size_t)(band + c) * HD + q * 8;
        short8 hH[4], hL[4];
#pragma unroll
        for (int ks = 0; ks < 4; ++ks) {
            hH[ks] = *(const short8*)(h_hi + rb + ks * 32);
            hL[ks] = *(const short8*)(h_lo + rb + ks * 32);
        }
#pragma unroll
        for (int ks = 0; ks < 4; ++ks) {
            short8 b = *(const short8*)(fb + ks * 512);
            acc = MFMA(hH[ks], b, acc);
            acc = MFMA(hL[ks], b, acc);
        }
#pragma unroll
        for (int ks = 0; ks < 4; ++ks) {
            int a = c * 128 + (((ks * 4 + q) ^ c) << 3);
            short8 sH = *(const short8*)&sHi[a];
            short8 sL = *(const short8*)&sLo[a];
            short8 b = *(const short8*)(fb + (4 + ks) * 512);
            acc = MFMA(sH, b, acc);
            acc = MFMA(sL, b, acc);
        }
    }
    float alv[4];
#pragma unroll
    for (int reg = 0; reg < 4; ++reg) alv[reg] = (cnt[band + q * 4 + reg] > 0) ? 1.f : 0.f;
    {
        int col = w * 16 + c;
        float u1b = ub1[col], cc = c2l[col];
#pragma unroll
        for (int reg = 0; reg < 4; ++reg) {
            int r16 = q * 4 + reg;
            float t = fmaxf(acc[reg] + u1b + alv[reg] * cc, 0.f);
            u16 hi, lo;
            split2(t, hi, lo);
            int a = r16 * 128 + (((col >> 3) ^ r16) << 3) + (col & 7);
            tHi[a] = hi;
            tLo[a] = lo;
        }
    }
    __syncthreads();
    // G2
    f32x4 acc2 = {0, 0, 0, 0};
    {
        const u16* fb = fG2l + (size_t)w * 4 * 512 + lane * 8;
#pragma unroll
        for (int ks = 0; ks < 4; ++ks) {
            int a = c * 128 + (((ks * 4 + q) ^ c) << 3);
            short8 aHh = *(const short8*)&tHi[a];
            short8 aLl = *(const short8*)&tLo[a];
            short8 b = *(const short8*)(fb + ks * 512);
            acc2 = MFMA(aHh, b, acc2);
            acc2 = MFMA(aLl, b, acc2);
        }
    }
    // residual + LN
    float vv[4];
    {
        int col = w * 16 + c;
        float u2b = ub2[col];
#pragma unroll
        for (int reg = 0; reg < 4; ++reg) {
            size_t idx = (size_t)(band + q * 4 + reg) * HD + col;
            float hres = bf2f(h_hi[idx]) + bf2f(h_lo[idx]);
            vv[reg] = acc2[reg] + u2b + hres;
        }
    }
#pragma unroll
    for (int reg = 0; reg < 4; ++reg) {
        float s = vv[reg];
        float s2 = vv[reg] * vv[reg];
        for (int m = 1; m < 16; m <<= 1) {
            s += __shfl_xor(s, m);
            s2 += __shfl_xor(s2, m);
        }
        if (c == 0) {
            red[q * 4 + reg][w][0] = s;
            red[q * 4 + reg][w][1] = s2;
        }
    }
    __syncthreads();
    float mu[4], rs[4];
#pragma unroll
    for (int reg = 0; reg < 4; ++reg) {
        int r16 = q * 4 + reg;
        float S1 = 0.f, S2 = 0.f;
#pragma unroll
        for (int ww = 0; ww < 8; ++ww) {
            S1 += red[r16][ww][0];
            S2 += red[r16][ww][1];
        }
        float m = S1 * (1.f / HD);
        float var = S2 * (1.f / HD) - m * m;
        mu[reg] = m;
        rs[reg] = rsqrtf(var + LN_EPS);
    }
    {
        int col = w * 16 + c;
        float gg = g[col], bv = bb[col];
#pragma unroll
        for (int reg = 0; reg < 4; ++reg) {
            int r16 = q * 4 + reg;
            float o = (vv[reg] - mu[reg]) * rs[reg] * gg + bv;
            u16 hi, lo;
            split2(o, hi, lo);
            int a = r16 * 128 + (((col >> 3) ^ r16) << 3) + (col & 7);
            tHi[a] = hi;
            tLo[a] = lo;
            if (!LAST) {
                size_t idx = (size_t)(band + r16) * HD + col;
                h_hi[idx] = hi;
                h_lo[idx] = lo;
            }
        }
    }
    __syncthreads();
    short8 aH3[4], aL3[4];
#pragma unroll
    for (int ks = 0; ks < 4; ++ks) {
        int a = c * 128 + (((ks * 4 + q) ^ c) << 3);
        aH3[ks] = *(const short8*)&tHi[a];
        aL3[ks] = *(const short8*)&tLo[a];
    }
    if (!LAST) {
#pragma unroll
        for (int i = 0; i < 2; ++i) {
            int ctg = w * 2 + i;
            const u16* fb = fPQn + (size_t)ctg * 4 * 512 + lane * 8;
            f32x4 a3 = {0, 0, 0, 0};
#pragma unroll
            for (int ks = 0; ks < 4; ++ks) {
                short8 b = *(const short8*)(fb + ks * 512);
                a3 = MFMA(aH3[ks], b, a3);
                a3 = MFMA(aL3[ks], b, a3);
            }
            int col = ctg * 16 + c;
            if (ctg < 8) {
                float bias = nb1[col];
#pragma unroll
                for (int reg = 0; reg < 4; ++reg)
                    PQout[(size_t)(band + q * 4 + reg) * HD + col] = a3[reg] + bias;
            } else {
                int colq = col - 128;
#pragma unroll
                for (int reg = 0; reg < 4; ++reg)
                    Qout[(size_t)(band + q * 4 + reg) * HD + colq] = f2bf(a3[reg]);
            }
        }
    } else {
        float part[4];
        {
            const u16* fb = fDec + (size_t)w * 4 * 512 + lane * 8;
            f32x4 a3 = {0, 0, 0, 0};
#pragma unroll
            for (int ks = 0; ks < 4; ++ks) {
                short8 b = *(const short8*)(fb + ks * 512);
                a3 = MFMA(aH3[ks], b, a3);
                a3 = MFMA(aL3[ks], b, a3);
            }
            int col = w * 16 + c;
            float w2v = dw2[col], b1v = db1[col];
#pragma unroll
            for (int reg = 0; reg < 4; ++reg) part[reg] = fmaxf(a3[reg] + b1v, 0.f) * w2v;
        }
#pragma unroll
        for (int reg = 0; reg < 4; ++reg) {
            float s = part[reg];
            for (int m = 1; m < 16; m <<= 1) s += __shfl_xor(s, m);
            if (c == 0) red[q * 4 + reg][w][0] = s;
        }
        __syncthreads();
        if (tid < 16) {
            float s = db2[0];
#pragma unroll
            for (int ww = 0; ww < 8; ++ww) s += red[tid][ww][0];
            out[band + tid] = s;
        }
    }
}

// ================= args struct =================

struct MegaArgs {
    const float* x;
    const int* srcp;
    const int* tgtp;
    const float* eattr;
    const float* enc_w1;
    const float* enc_b1;
    const float* enc_w2;
    const float* enc_b2;
    const float* msg_w1;
    const float* msg_b1;
    const float* msg_w2;
    const float* msg_b2;
    const float* upd_w1;
    const float* upd_b1;
    const float* upd_w2;
    const float* upd_b2;
    const float* ln_g;
    const float* ln_b;
    const float* dec_w1;
    const float* dec_b1;
    const float* dec_w2;
    const float* dec_b2;
    float* out;
    float4* sea;
    float* PQf0;
    float* PQf1;
    u16* Qb0;
    u16* Qb1;
    u16* h_hi;
    u16* h_lo;
    int* cnt;
    float* M2;
    float* c2;
    u16* fG1;
    u16* fG2;
    u16* fPQ;
    u16* fDec;
    u16* fEnc;
};

// ================= cooperative mega kernel =================

__global__ __launch_bounds__(NTHR, 6) void k_mega(MegaArgs A) {
    cg::grid_group grid = cg::this_grid();
    __shared__ u16 sHi[2048], sLo[2048];
    __shared__ u16 tHi[2048], tLo[2048];
    __shared__ float red[16][8][2];
    int tid = threadIdx.x;
    int band = blockIdx.x * 16;
    int gid = blockIdx.x * NTHR + tid;

    // Phase A
    prep_item(gid, A.msg_w2, A.msg_b2, A.upd_w1, A.upd_w2, A.msg_w1, A.dec_w1, A.enc_w2, A.M2, A.c2,
              A.cnt, A.fG2, A.fPQ, A.fDec, A.fEnc);
    grid.sync();
    // Phase B: fG1 + scatter + encoder
    if (gid < 16384) fg1_item(gid, A.upd_w1, A.M2, A.fG1);
    for (int e = gid; e < NE; e += TOTTHR) {
        int t = A.tgtp[e];
        int pos = atomicAdd(&A.cnt[t], 1);
        if (pos < CAP) {
            A.sea[t * CAP + pos] = make_float4(A.eattr[e * 3], A.eattr[e * 3 + 1], A.eattr[e * 3 + 2],
                                               __uint_as_float((unsigned)A.srcp[e]));
        }
    }
    enc_body(band, tid, A.x, A.enc_w1, A.enc_b1, A.fEnc, A.enc_b2, A.fPQ, A.msg_b1, A.h_hi, A.h_lo,
             A.PQf0, A.Qb0, tHi, tLo);
    grid.sync();
    // Phase C: layers
    const float* PQin = A.PQf0;
    const u16* Qin = A.Qb0;
    float* PQout = A.PQf1;
    u16* Qout = A.Qb1;
    for (int l = 0; l < NL; ++l) {
        bool LAST = (l == NL - 1);
        layer_body(band, tid, LAST, PQin, Qin, A.cnt, A.sea,
                   A.msg_w1 + (size_t)l * (2 * HD + EDIM) * HD + (size_t)2 * HD * HD, A.h_hi, A.h_lo,
                   A.fG1 + (size_t)l * 32768, A.fG2 + (size_t)l * 16384, A.upd_b1 + l * HD,
                   A.c2 + l * HD, A.upd_b2 + l * HD, A.ln_g + l * HD, A.ln_b + l * HD,
                   LAST ? nullptr : (A.fPQ + (size_t)(l + 1) * 32768),
                   LAST ? nullptr : (A.msg_b1 + (size_t)(l + 1) * HD), PQout, Qout, A.fDec, A.dec_b1,
                   A.dec_w2, A.dec_b2, A.out, sHi, sLo, tHi, tLo, red);
        if (!LAST) {
            grid.sync();
            const float* tp = PQin;
            PQin = PQout;
            PQout = (float*)tp;
            const u16* tq = Qin;
            Qin = Qout;
            Qout = (u16*)tq;
        }
    }
}

// ================= fallback multi-kernel path =================

__global__ __launch_bounds__(256) void k_prep(
    const float* __restrict__ msg_w2, const float* __restrict__ msg_b2, const float* __restrict__ upd_w1,
    const float* __restrict__ upd_w2, const float* __restrict__ msg_w1, const float* __restrict__ dec_w1,
    const float* __restrict__ enc_w2, float* __restrict__ M2, float* __restrict__ c2, int* __restrict__ cnt,
    u16* __restrict__ fG2, u16* __restrict__ fPQ, u16* __restrict__ fDec, u16* __restrict__ fEnc) {
    int idx = blockIdx.x * 256 + threadIdx.x;
    prep_item(idx, msg_w2, msg_b2, upd_w1, upd_w2, msg_w1, dec_w1, enc_w2, M2, c2, cnt, fG2, fPQ,
              fDec, fEnc);
}

__global__ __launch_bounds__(256) void k_scatfrag(
    const int* __restrict__ src, const int* __restrict__ tgt, const float* __restrict__ ea,
    int* __restrict__ cnt, float4* __restrict__ sea, const float* __restrict__ upd_w1,
    const float* __restrict__ M2, u16* __restrict__ fG1) {
    if (blockIdx.x < 64) {
        fg1_item(blockIdx.x * 256 + threadIdx.x, upd_w1, M2, fG1);
    } else {
        int e = (blockIdx.x - 64) * 256 + threadIdx.x;
        if (e >= NE) return;
        int t = tgt[e];
        int pos = atomicAdd(&cnt[t], 1);
        if (pos < CAP) {
            sea[t * CAP + pos] =
                make_float4(ea[e * 3], ea[e * 3 + 1], ea[e * 3 + 2], __uint_as_float((unsigned)src[e]));
        }
    }
}

__global__ __launch_bounds__(512) void k_enc(const float* __restrict__ x, const float* __restrict__ ew1,
                                             const float* __restrict__ eb1, const u16* __restrict__ fEnc,
                                             const float* __restrict__ eb2, const u16* __restrict__ fPQ0,
                                             const float* __restrict__ mb1, u16* __restrict__ h_hi,
                                             u16* __restrict__ h_lo, float* __restrict__ PQf,
                                             u16* __restrict__ Qb) {
    __shared__ u16 tHi[2048], tLo[2048];
    enc_body(blockIdx.x * 16, threadIdx.x, x, ew1, eb1, fEnc, eb2, fPQ0, mb1, h_hi, h_lo, PQf, Qb,
             tHi, tLo);
}

template <bool LAST>
__global__ __launch_bounds__(512) void k_layer(
    const float* __restrict__ PQf_in, const u16* __restrict__ Qb_in, const int* __restrict__ cnt,
    const float4* __restrict__ sea, const float* __restrict__ wc, u16* __restrict__ h_hi,
    u16* __restrict__ h_lo, const u16* __restrict__ fG1, const u16* __restrict__ fG2,
    const float* __restrict__ ub1, const float* __restrict__ c2l, const float* __restrict__ ub2,
    const float* __restrict__ g, const float* __restrict__ bb, const u16* __restrict__ fPQ,
    const float* __restrict__ nb1, float* __restrict__ PQf_out, u16* __restrict__ Qb_out,
    const u16* __restrict__ fDec, const float* __restrict__ db1, const float* __restrict__ dw2,
    const float* __restrict__ db2, float* __restrict__ out) {
    __shared__ u16 sHi[2048], sLo[2048];
    __shared__ u16 tHi[2048], tLo[2048];
    __shared__ float red[16][8][2];
    layer_body(blockIdx.x * 16, threadIdx.x, LAST, PQf_in, Qb_in, cnt, sea, wc, h_hi, h_lo, fG1, fG2,
               ub1, c2l, ub2, g, bb, fPQ, nb1, PQf_out, Qb_out, fDec, db1, dw2, db2, out, sHi, sLo,
               tHi, tLo, red);
}

// ================= launch =================

extern "C" void kernel_launch(void* const* d_in, const int* in_sizes, int n_in,
                              void* d_out, int out_size, void* d_ws, size_t ws_size,
                              hipStream_t stream) {
    char* base = (char*)d_ws;
    size_t off = 0;
    auto alloc = [&](size_t bytes) -> void* {
        off = (off + 15) & ~(size_t)15;
        void* p = base + off;
        off += bytes;
        return p;
    };
    MegaArgs A;
    A.x = (const float*)d_in[0];
    const int* eidx = (const int*)d_in[1];
    A.srcp = eidx;
    A.tgtp = eidx + NE;
    A.eattr = (const float*)d_in[2];
    A.enc_w1 = (const float*)d_in[3];
    A.enc_b1 = (const float*)d_in[4];
    A.enc_w2 = (const float*)d_in[5];
    A.enc_b2 = (const float*)d_in[6];
    A.msg_w1 = (const float*)d_in[7];
    A.msg_b1 = (const float*)d_in[8];
    A.msg_w2 = (const float*)d_in[9];
    A.msg_b2 = (const float*)d_in[10];
    A.upd_w1 = (const float*)d_in[11];
    A.upd_b1 = (const float*)d_in[12];
    A.upd_w2 = (const float*)d_in[13];
    A.upd_b2 = (const float*)d_in[14];
    A.ln_g = (const float*)d_in[15];
    A.ln_b = (const float*)d_in[16];
    A.dec_w1 = (const float*)d_in[17];
    A.dec_b1 = (const float*)d_in[18];
    A.dec_w2 = (const float*)d_in[19];
    A.dec_b2 = (const float*)d_in[20];
    A.out = (float*)d_out;
    A.sea = (float4*)alloc((size_t)NN * CAP * 16);
    A.PQf0 = (float*)alloc((size_t)NN * HD * 4);
    A.PQf1 = (float*)alloc((size_t)NN * HD * 4);
    A.Qb0 = (u16*)alloc((size_t)NN * HD * 2);
    A.Qb1 = (u16*)alloc((size_t)NN * HD * 2);
    A.h_hi = (u16*)alloc((size_t)NN * HD * 2);
    A.h_lo = (u16*)alloc((size_t)NN * HD * 2);
    A.cnt = (int*)alloc((size_t)NN * 4);
    A.M2 = (float*)alloc((size_t)NL * HD * HD * 4);
    A.c2 = (float*)alloc((size_t)NL * HD * 4);
    A.fG1 = (u16*)alloc((size_t)131072 * 2);
    A.fG2 = (u16*)alloc((size_t)65536 * 2);
    A.fPQ = (u16*)alloc((size_t)131072 * 2);
    A.fDec = (u16*)alloc((size_t)16384 * 2);
    A.fEnc = (u16*)alloc((size_t)16384 * 2);

    void* kargs[] = {&A};
    hipError_t err =
        hipLaunchCooperativeKernel((void*)k_mega, dim3(GRID_C), dim3(NTHR), kargs, 0, stream);
    if (err != hipSuccess) {
        // fallback: proven 7-dispatch path
        (void)hipGetLastError();  // clear sticky error
        k_prep<<<410, 256, 0, stream>>>(A.msg_w2, A.msg_b2, A.upd_w1, A.upd_w2, A.msg_w1, A.dec_w1,
                                        A.enc_w2, A.M2, A.c2, A.cnt, A.fG2, A.fPQ, A.fDec, A.fEnc);
        k_scatfrag<<<64 + (NE + 255) / 256, 256, 0, stream>>>(A.srcp, A.tgtp, A.eattr, A.cnt, A.sea,
                                                              A.upd_w1, A.M2, A.fG1);
        k_enc<<<NN / 16, 512, 0, stream>>>(A.x, A.enc_w1, A.enc_b1, A.fEnc, A.enc_b2, A.fPQ,
                                           A.msg_b1, A.h_hi, A.h_lo, A.PQf0, A.Qb0);
        float* PQin = A.PQf0;
        u16* Qin = A.Qb0;
        float* PQout = A.PQf1;
        u16* Qout = A.Qb1;
        for (int l = 0; l < NL; ++l) {
            const float* wc = A.msg_w1 + (size_t)l * (2 * HD + EDIM) * HD + (size_t)2 * HD * HD;
            if (l < NL - 1) {
                k_layer<false><<<NN / 16, 512, 0, stream>>>(
                    PQin, Qin, A.cnt, A.sea, wc, A.h_hi, A.h_lo, A.fG1 + (size_t)l * 32768,
                    A.fG2 + (size_t)l * 16384, A.upd_b1 + l * HD, A.c2 + l * HD, A.upd_b2 + l * HD,
                    A.ln_g + l * HD, A.ln_b + l * HD, A.fPQ + (size_t)(l + 1) * 32768,
                    A.msg_b1 + (size_t)(l + 1) * HD, PQout, Qout, nullptr, nullptr, nullptr, nullptr,
                    nullptr);
            } else {
                k_layer<true><<<NN / 16, 512, 0, stream>>>(
                    PQin, Qin, A.cnt, A.sea, wc, A.h_hi, A.h_lo, A.fG1 + (size_t)l * 32768,
                    A.fG2 + (size_t)l * 16384, A.upd_b1 + l * HD, A.c2 + l * HD, A.upd_b2 + l * HD,
                    A.ln_g + l * HD, A.ln_b + l * HD, nullptr, nullptr, nullptr, nullptr, A.fDec,
                    A.dec_b1, A.dec_w2, A.dec_b2, A.out);
            }
            float* tf = PQin;
            PQin = PQout;
            PQout = tf;
            u16* tq = Qin;
            Qin = Qout;
            Qout = tq;
        }
    }
}

// Round 11
// 285.327 us; speedup vs baseline: 3.0602x; 3.0602x over previous
//
#include <hip/hip_runtime.h>

#define NN 10000
#define NE 400000
#define HD 128
#define NIN 6
#define EDIM 3
#define NL 4
#define CAP 96
#define LN_EPS 1e-5f

typedef unsigned short u16;
using short8 = __attribute__((ext_vector_type(8))) short;
using f32x4 = __attribute__((ext_vector_type(4))) float;

__device__ __forceinline__ u16 f2bf(float x) {
    unsigned u = __float_as_uint(x);
    return (u16)((u + 0x7fff + ((u >> 16) & 1)) >> 16);
}
__device__ __forceinline__ float bf2f(u16 h) { return __uint_as_float(((unsigned)h) << 16); }
__device__ __forceinline__ void split2(float x, u16& hi, u16& lo) {
    hi = f2bf(x);
    lo = f2bf(x - bf2f(hi));
}
#define MFMA(a, b, c) __builtin_amdgcn_mfma_f32_16x16x32_bf16((a), (b), (c), 0, 0, 0)

// ---------------- k_prep: M2 = msg_w2@U1b, c2 = msg_b2@U1b (lane-coalesced), cnt zero --------

__global__ __launch_bounds__(256) void k_prep(const float* __restrict__ msg_w2, const float* __restrict__ msg_b2,
                                              const float* __restrict__ upd_w1, float* __restrict__ M2,
                                              float* __restrict__ c2, int* __restrict__ cnt) {
    int idx = blockIdx.x * 256 + threadIdx.x;
    if (idx < 65536) {
        int l = idx >> 14, rem = idx & 16383, i = rem >> 7, jj = rem & 127;
        const float* U1b = upd_w1 + (size_t)l * 2 * HD * HD + (size_t)HD * HD;
        const float* W2 = msg_w2 + (size_t)l * HD * HD + (size_t)i * HD;
        float acc = 0.f;
        for (int t = 0; t < HD; ++t) acc += W2[t] * U1b[(size_t)t * HD + jj];
        M2[idx] = acc;
    } else if (idx < 66048) {
        int r = idx - 65536;
        int l = r >> 7, jj = r & 127;
        const float* U1b = upd_w1 + (size_t)l * 2 * HD * HD + (size_t)HD * HD;
        const float* b2 = msg_b2 + l * HD;
        float acc = 0.f;
        for (int t = 0; t < HD; ++t) acc += b2[t] * U1b[(size_t)t * HD + jj];
        c2[r] = acc;
    } else if (idx < 76048) {
        cnt[idx - 66048] = 0;
    }
}

// ---------------- k_frag: pack B-fragments [ct][ks][lane][8] bf16 ----------------

__global__ __launch_bounds__(256) void k_frag(const float* __restrict__ upd_w1, const float* __restrict__ M2,
                                              const float* __restrict__ upd_w2, const float* __restrict__ msg_w1,
                                              const float* __restrict__ dec_w1, const float* __restrict__ enc_w2,
                                              u16* __restrict__ fG1, u16* __restrict__ fG2, u16* __restrict__ fPQ,
                                              u16* __restrict__ fDec, u16* __restrict__ fEnc) {
    int g = blockIdx.x * 256 + threadIdx.x;
    if (g < 16384) {
        int l = g >> 12, r = g & 4095;
        int ct = r >> 9, ks = (r >> 6) & 7, lane = r & 63;
        int n = ct * 16 + (lane & 15), kb = ks * 32 + ((lane >> 4) << 3);
        u16* dst = fG1 + (size_t)g * 8;
        const float* U = upd_w1 + (size_t)l * 256 * 128;
        const float* Ml = M2 + (size_t)l * 128 * 128;
#pragma unroll
        for (int j = 0; j < 8; ++j) {
            int k = kb + j;
            float v = (k < 128) ? U[(size_t)k * 128 + n] : Ml[(size_t)(k - 128) * 128 + n];
            dst[j] = f2bf(v);
        }
    } else if (g < 24576) {
        int gg = g - 16384;
        int l = gg >> 11, r = gg & 2047;
        int ct = r >> 8, ks = (r >> 6) & 3, lane = r & 63;
        int n = ct * 16 + (lane & 15), kb = ks * 32 + ((lane >> 4) << 3);
        u16* dst = fG2 + (size_t)gg * 8;
        const float* W = upd_w2 + (size_t)l * 128 * 128;
#pragma unroll
        for (int j = 0; j < 8; ++j) dst[j] = f2bf(W[(size_t)(kb + j) * 128 + n]);
    } else if (g < 40960) {
        int gg = g - 24576;
        int li = gg >> 12, r = gg & 4095;
        int ct = r >> 8, ks = (r >> 6) & 3, lane = r & 63;
        int n = ct * 16 + (lane & 15), kb = ks * 32 + ((lane >> 4) << 3);
        u16* dst = fPQ + (size_t)gg * 8;
        const float* W = msg_w1 + (size_t)li * (2 * HD + EDIM) * HD;
#pragma unroll
        for (int j = 0; j < 8; ++j) {
            int k = kb + j;
            float v = (n < 128) ? W[(size_t)k * 128 + n] : W[(size_t)(128 + k) * 128 + (n - 128)];
            dst[j] = f2bf(v);
        }
    } else if (g < 43008) {
        int r = g - 40960;
        int ct = r >> 8, ks = (r >> 6) & 3, lane = r & 63;
        int n = ct * 16 + (lane & 15), kb = ks * 32 + ((lane >> 4) << 3);
        u16* dst = fDec + (size_t)r * 8;
#pragma unroll
        for (int j = 0; j < 8; ++j) dst[j] = f2bf(dec_w1[(size_t)(kb + j) * 128 + n]);
    } else if (g < 45056) {
        int r = g - 43008;
        int ct = r >> 8, ks = (r >> 6) & 3, lane = r & 63;
        int n = ct * 16 + (lane & 15), kb = ks * 32 + ((lane >> 4) << 3);
        u16* dst = fEnc + (size_t)r * 8;
#pragma unroll
        for (int j = 0; j < 8; ++j) dst[j] = f2bf(enc_w2[(size_t)(kb + j) * 128 + n]);
    }
}

// ---------------- scatter: buckets, attrs+src packed in one float4 ----------------

__global__ __launch_bounds__(256) void k_scatter(const int* __restrict__ src, const int* __restrict__ tgt,
                                                 const float* __restrict__ ea, int* __restrict__ cnt,
                                                 float4* __restrict__ sea) {
    int e = blockIdx.x * 256 + threadIdx.x;
    if (e >= NE) return;
    int t = tgt[e];
    int pos = atomicAdd(&cnt[t], 1);
    if (pos < CAP) {
        sea[t * CAP + pos] =
            make_float4(ea[e * 3], ea[e * 3 + 1], ea[e * 3 + 2], __uint_as_float((unsigned)src[e]));
    }
}

// ---------------- encoder (512 thr / 8 waves): GEMM1 VALU -> MFMA GEMM2 -> MFMA PQ0 ----------

__global__ __launch_bounds__(512) void k_enc(const float* __restrict__ x, const float* __restrict__ ew1,
                                             const float* __restrict__ eb1, const u16* __restrict__ fEnc,
                                             const float* __restrict__ eb2, const u16* __restrict__ fPQ0,
                                             const float* __restrict__ mb1, u16* __restrict__ h_hi,
                                             u16* __restrict__ h_lo, float* __restrict__ PQf,
                                             u16* __restrict__ Qb) {
    __shared__ u16 tHi[2048], tLo[2048];
    int tid = threadIdx.x, w = tid >> 6, lane = tid & 63, q = lane >> 4, c = lane & 15;
    int band = blockIdx.x * 16;
    // GEMM1: wave w covers cols [w*16, w*16+16)
    {
        int col = w * 16 + c;
        float wv[NIN];
#pragma unroll
        for (int k = 0; k < NIN; ++k) wv[k] = ew1[k * HD + col];
        float ebv = eb1[col];
#pragma unroll
        for (int reg = 0; reg < 4; ++reg) {
            int row = band + q * 4 + reg;
            float t = ebv;
#pragma unroll
            for (int k = 0; k < NIN; ++k) t += x[(size_t)row * NIN + k] * wv[k];
            t = fmaxf(t, 0.f);
            u16 hi, lo;
            split2(t, hi, lo);
            int r16 = q * 4 + reg;
            int a = r16 * 128 + (((col >> 3) ^ r16) << 3) + (col & 7);
            tHi[a] = hi;
            tLo[a] = lo;
        }
    }
    __syncthreads();
    short8 aH[4], aL[4];
#pragma unroll
    for (int ks = 0; ks < 4; ++ks) {
        int a = c * 128 + (((ks * 4 + q) ^ c) << 3);
        aH[ks] = *(const short8*)&tHi[a];
        aL[ks] = *(const short8*)&tLo[a];
    }
    // GEMM2: 1 ctg per wave
    f32x4 acc = {0, 0, 0, 0};
    {
        const u16* fb = fEnc + (size_t)w * 4 * 512 + lane * 8;
#pragma unroll
        for (int ks = 0; ks < 4; ++ks) {
            short8 b = *(const short8*)(fb + ks * 512);
            acc = MFMA(aH[ks], b, acc);
            acc = MFMA(aL[ks], b, acc);
        }
    }
    __syncthreads();
    {
        int col = w * 16 + c;
        float ebv = eb2[col];
#pragma unroll
        for (int reg = 0; reg < 4; ++reg) {
            int r16 = q * 4 + reg, row = band + r16;
            float hval = acc[reg] + ebv;
            u16 hi, lo;
            split2(hval, hi, lo);
            h_hi[(size_t)row * HD + col] = hi;
            h_lo[(size_t)row * HD + col] = lo;
            int a = r16 * 128 + (((col >> 3) ^ r16) << 3) + (col & 7);
            tHi[a] = hi;
            tLo[a] = lo;
        }
    }
    __syncthreads();
#pragma unroll
    for (int ks = 0; ks < 4; ++ks) {
        int a = c * 128 + (((ks * 4 + q) ^ c) << 3);
        aH[ks] = *(const short8*)&tHi[a];
        aL[ks] = *(const short8*)&tLo[a];
    }
    // PQ0: 2 ctg per wave
#pragma unroll
    for (int i = 0; i < 2; ++i) {
        int ctg = w * 2 + i;
        const u16* fb = fPQ0 + (size_t)ctg * 4 * 512 + lane * 8;
        f32x4 a3 = {0, 0, 0, 0};
#pragma unroll
        for (int ks = 0; ks < 4; ++ks) {
            short8 b = *(const short8*)(fb + ks * 512);
            a3 = MFMA(aH[ks], b, a3);
            a3 = MFMA(aL[ks], b, a3);
        }
        int col = ctg * 16 + c;
        if (ctg < 8) {
            float bias = mb1[col];
#pragma unroll
            for (int reg = 0; reg < 4; ++reg)
                PQf[(size_t)(band + q * 4 + reg) * HD + col] = a3[reg] + bias;
        } else {
            int colq = col - 128;
#pragma unroll
            for (int reg = 0; reg < 4; ++reg)
                Qb[(size_t)(band + q * 4 + reg) * HD + colq] = f2bf(a3[reg]);
        }
    }
}

// ------- fused layer (512 thr / 8 waves): edge-gather -> G1 -> G2 -> LN -> (PQ next | dec) -----

template <bool LAST>
__global__ __launch_bounds__(512) void k_layer(
    const float* __restrict__ PQf_in, const u16* __restrict__ Qb_in,
    const int* __restrict__ cnt, const float4* __restrict__ sea, const float* __restrict__ wc,
    u16* __restrict__ h_hi, u16* __restrict__ h_lo,
    const u16* __restrict__ fG1, const u16* __restrict__ fG2,
    const float* __restrict__ ub1, const float* __restrict__ c2l, const float* __restrict__ ub2,
    const float* __restrict__ g, const float* __restrict__ bb,
    const u16* __restrict__ fPQ, const float* __restrict__ nb1,
    float* __restrict__ PQf_out, u16* __restrict__ Qb_out,
    const u16* __restrict__ fDec, const float* __restrict__ db1, const float* __restrict__ dw2,
    const float* __restrict__ db2, float* __restrict__ out) {
    __shared__ u16 sHi[2048], sLo[2048];
    __shared__ u16 tHi[2048], tLo[2048];
    __shared__ float red[16][8][2];
    int tid = threadIdx.x, w = tid >> 6, lane = tid & 63, q = lane >> 4, c = lane & 15;
    int band = blockIdx.x * 16;
    int j = lane * 2;
    // ======== edge phase: wave w handles rows w*2, w*2+1 ========
    {
        float2 wcr0 = *(const float2*)(wc + j);
        float2 wcr1 = *(const float2*)(wc + HD + j);
        float2 wcr2 = *(const float2*)(wc + 2 * HD + j);
#pragma unroll
        for (int i = 0; i < 2; ++i) {
            int r16 = w * 2 + i;
            int n = __builtin_amdgcn_readfirstlane(band + r16);
            int cn = cnt[n];
            float invn = 1.0f / fmaxf((float)cn, 1.0f);
            int cle = __builtin_amdgcn_readfirstlane(cn < CAP ? cn : CAP);
            float2 p = *(const float2*)(PQf_in + (size_t)n * HD + j);
            float acc0 = 0.f, acc1 = 0.f;
            const float4* bucket = sea + (size_t)n * CAP;
            auto edge1 = [&](float4 A) {
                int sv = (int)__float_as_uint(A.w);
                float c0 = A.x * wcr0.x + A.y * wcr1.x + A.z * wcr2.x;
                float c1 = A.x * wcr0.y + A.y * wcr1.y + A.z * wcr2.y;
                unsigned u = *(const unsigned*)(Qb_in + (size_t)sv * HD + j);
                acc0 += fmaxf(p.x + __uint_as_float(u << 16) + c0, 0.f);
                acc1 += fmaxf(p.y + __uint_as_float(u & 0xffff0000u) + c1, 0.f);
            };
            int e = 0;
            for (; e + 3 < cle; e += 4) {
                float4 A0 = bucket[e], A1 = bucket[e + 1], A2 = bucket[e + 2], A3 = bucket[e + 3];
                edge1(A0);
                edge1(A1);
                edge1(A2);
                edge1(A3);
            }
            for (; e < cle; ++e) edge1(bucket[e]);
            float v0 = acc0 * invn, v1 = acc1 * invn;
            u16 h0, l0, h1, l1;
            split2(v0, h0, l0);
            split2(v1, h1, l1);
            int a = r16 * 128 + (((j >> 3) ^ r16) << 3) + (j & 7);
            *(ushort2*)&sHi[a] = make_ushort2(h0, h1);
            *(ushort2*)&sLo[a] = make_ushort2(l0, l1);
        }
    }
    __syncthreads();
    // ======== G1: A = [h (global) | S (LDS)], 1 ctg per wave ========
    short8 aH[8], aL[8];
    {
        size_t rb = (size_t)(band + c) * HD + q * 8;
#pragma unroll
        for (int ks = 0; ks < 4; ++ks) {
            aH[ks] = *(const short8*)(h_hi + rb + ks * 32);
            aL[ks] = *(const short8*)(h_lo + rb + ks * 32);
            int a = c * 128 + (((ks * 4 + q) ^ c) << 3);
            aH[4 + ks] = *(const short8*)&sHi[a];
            aL[4 + ks] = *(const short8*)&sLo[a];
        }
    }
    f32x4 acc = {0, 0, 0, 0};
    {
        const u16* fb = fG1 + (size_t)w * 8 * 512 + lane * 8;
#pragma unroll
        for (int ks = 0; ks < 8; ++ks) {
            short8 b = *(const short8*)(fb + ks * 512);
            acc = MFMA(aH[ks], b, acc);
            acc = MFMA(aL[ks], b, acc);
        }
    }
    float alv[4];
#pragma unroll
    for (int reg = 0; reg < 4; ++reg) alv[reg] = (cnt[band + q * 4 + reg] > 0) ? 1.f : 0.f;
    {
        int col = w * 16 + c;
        float u1b = ub1[col], cc = c2l[col];
#pragma unroll
        for (int reg = 0; reg < 4; ++reg) {
            int r16 = q * 4 + reg;
            float t = fmaxf(acc[reg] + u1b + alv[reg] * cc, 0.f);
            u16 hi, lo;
            split2(t, hi, lo);
            int a = r16 * 128 + (((col >> 3) ^ r16) << 3) + (col & 7);
            tHi[a] = hi;
            tLo[a] = lo;
        }
    }
    __syncthreads();
    // ======== G2: 1 ctg per wave ========
    short8 aH2[4], aL2[4];
#pragma unroll
    for (int ks = 0; ks < 4; ++ks) {
        int a = c * 128 + (((ks * 4 + q) ^ c) << 3);
        aH2[ks] = *(const short8*)&tHi[a];
        aL2[ks] = *(const short8*)&tLo[a];
    }
    f32x4 acc2 = {0, 0, 0, 0};
    {
        const u16* fb = fG2 + (size_t)w * 4 * 512 + lane * 8;
#pragma unroll
        for (int ks = 0; ks < 4; ++ks) {
            short8 b = *(const short8*)(fb + ks * 512);
            acc2 = MFMA(aH2[ks], b, acc2);
            acc2 = MFMA(aL2[ks], b, acc2);
        }
    }
    // ======== residual + LN ========
    float vv[4];
    {
        int col = w * 16 + c;
        float u2b = ub2[col];
#pragma unroll
        for (int reg = 0; reg < 4; ++reg) {
            size_t idx = (size_t)(band + q * 4 + reg) * HD + col;
            float hres = bf2f(h_hi[idx]) + bf2f(h_lo[idx]);
            vv[reg] = acc2[reg] + u2b + hres;
        }
    }
#pragma unroll
    for (int reg = 0; reg < 4; ++reg) {
        float s = vv[reg];
        float s2 = vv[reg] * vv[reg];
        for (int m = 1; m < 16; m <<= 1) {
            s += __shfl_xor(s, m);
            s2 += __shfl_xor(s2, m);
        }
        if (c == 0) {
            red[q * 4 + reg][w][0] = s;
            red[q * 4 + reg][w][1] = s2;
        }
    }
    __syncthreads();
    float mu[4], rs[4];
#pragma unroll
    for (int reg = 0; reg < 4; ++reg) {
        int r16 = q * 4 + reg;
        float S1 = 0.f, S2 = 0.f;
#pragma unroll
        for (int ww = 0; ww < 8; ++ww) {
            S1 += red[r16][ww][0];
            S2 += red[r16][ww][1];
        }
        float m = S1 * (1.f / HD);
        float var = S2 * (1.f / HD) - m * m;
        mu[reg] = m;
        rs[reg] = rsqrtf(var + LN_EPS);
    }
    {
        int col = w * 16 + c;
        float gg = g[col], bv = bb[col];
#pragma unroll
        for (int reg = 0; reg < 4; ++reg) {
            int r16 = q * 4 + reg;
            float o = (vv[reg] - mu[reg]) * rs[reg] * gg + bv;
            u16 hi, lo;
            split2(o, hi, lo);
            int a = r16 * 128 + (((col >> 3) ^ r16) << 3) + (col & 7);
            tHi[a] = hi;
            tLo[a] = lo;
            if (!LAST) {
                size_t idx = (size_t)(band + r16) * HD + col;
                h_hi[idx] = hi;
                h_lo[idx] = lo;
            }
        }
    }
    __syncthreads();
    short8 aH3[4], aL3[4];
#pragma unroll
    for (int ks = 0; ks < 4; ++ks) {
        int a = c * 128 + (((ks * 4 + q) ^ c) << 3);
        aH3[ks] = *(const short8*)&tHi[a];
        aL3[ks] = *(const short8*)&tLo[a];
    }
    if (!LAST) {
        // PQ(next): 2 ctg per wave
#pragma unroll
        for (int i = 0; i < 2; ++i) {
            int ctg = w * 2 + i;
            const u16* fb = fPQ + (size_t)ctg * 4 * 512 + lane * 8;
            f32x4 a3 = {0, 0, 0, 0};
#pragma unroll
            for (int ks = 0; ks < 4; ++ks) {
                short8 b = *(const short8*)(fb + ks * 512);
                a3 = MFMA(aH3[ks], b, a3);
                a3 = MFMA(aL3[ks], b, a3);
            }
            int col = ctg * 16 + c;
            if (ctg < 8) {
                float bias = nb1[col];
#pragma unroll
                for (int reg = 0; reg < 4; ++reg)
                    PQf_out[(size_t)(band + q * 4 + reg) * HD + col] = a3[reg] + bias;
            } else {
                int colq = col - 128;
#pragma unroll
                for (int reg = 0; reg < 4; ++reg)
                    Qb_out[(size_t)(band + q * 4 + reg) * HD + colq] = f2bf(a3[reg]);
            }
        }
    } else {
        // decoder: 1 ctg per wave
        float part[4];
        {
            const u16* fb = fDec + (size_t)w * 4 * 512 + lane * 8;
            f32x4 a3 = {0, 0, 0, 0};
#pragma unroll
            for (int ks = 0; ks < 4; ++ks) {
                short8 b = *(const short8*)(fb + ks * 512);
                a3 = MFMA(aH3[ks], b, a3);
                a3 = MFMA(aL3[ks], b, a3);
            }
            int col = w * 16 + c;
            float w2v = dw2[col], b1v = db1[col];
#pragma unroll
            for (int reg = 0; reg < 4; ++reg) part[reg] = fmaxf(a3[reg] + b1v, 0.f) * w2v;
        }
#pragma unroll
        for (int reg = 0; reg < 4; ++reg) {
            float s = part[reg];
            for (int m = 1; m < 16; m <<= 1) s += __shfl_xor(s, m);
            if (c == 0) red[q * 4 + reg][w][0] = s;
        }
        __syncthreads();
        if (tid < 16) {
            float s = db2[0];
#pragma unroll
            for (int ww = 0; ww < 8; ++ww) s += red[tid][ww][0];
            out[band + tid] = s;
        }
    }
}

// ---------------- launch ----------------

extern "C" void kernel_launch(void* const* d_in, const int* in_sizes, int n_in,
                              void* d_out, int out_size, void* d_ws, size_t ws_size,
                              hipStream_t stream) {
    const float* x = (const float*)d_in[0];
    const int* eidx = (const int*)d_in[1];
    const float* eattr = (const float*)d_in[2];
    const float* enc_w1 = (const float*)d_in[3];
    const float* enc_b1 = (const float*)d_in[4];
    const float* enc_w2 = (const float*)d_in[5];
    const float* enc_b2 = (const float*)d_in[6];
    const float* msg_w1 = (const float*)d_in[7];
    const float* msg_b1 = (const float*)d_in[8];
    const float* msg_w2 = (const float*)d_in[9];
    const float* msg_b2 = (const float*)d_in[10];
    const float* upd_w1 = (const float*)d_in[11];
    const float* upd_b1 = (const float*)d_in[12];
    const float* upd_w2 = (const float*)d_in[13];
    const float* upd_b2 = (const float*)d_in[14];
    const float* ln_g = (const float*)d_in[15];
    const float* ln_b = (const float*)d_in[16];
    const float* dec_w1 = (const float*)d_in[17];
    const float* dec_b1 = (const float*)d_in[18];
    const float* dec_w2 = (const float*)d_in[19];
    const float* dec_b2 = (const float*)d_in[20];
    const int* srcp = eidx;
    const int* tgtp = eidx + NE;

    char* base = (char*)d_ws;
    size_t off = 0;
    auto alloc = [&](size_t bytes) -> void* {
        off = (off + 15) & ~(size_t)15;
        void* p = base + off;
        off += bytes;
        return p;
    };
    float4* sea = (float4*)alloc((size_t)NN * CAP * 16);
    float* PQf0 = (float*)alloc((size_t)NN * HD * 4);
    float* PQf1 = (float*)alloc((size_t)NN * HD * 4);
    u16* Qb0 = (u16*)alloc((size_t)NN * HD * 2);
    u16* Qb1 = (u16*)alloc((size_t)NN * HD * 2);
    u16* h_hi = (u16*)alloc((size_t)NN * HD * 2);
    u16* h_lo = (u16*)alloc((size_t)NN * HD * 2);
    int* cnt = (int*)alloc((size_t)NN * 4);
    float* M2 = (float*)alloc((size_t)NL * HD * HD * 4);
    float* c2 = (float*)alloc((size_t)NL * HD * 4);
    u16* fG1 = (u16*)alloc((size_t)131072 * 2);
    u16* fG2 = (u16*)alloc((size_t)65536 * 2);
    u16* fPQ = (u16*)alloc((size_t)131072 * 2);
    u16* fDec = (u16*)alloc((size_t)16384 * 2);
    u16* fEnc = (u16*)alloc((size_t)16384 * 2);

    k_prep<<<298, 256, 0, stream>>>(msg_w2, msg_b2, upd_w1, M2, c2, cnt);
    k_frag<<<176, 256, 0, stream>>>(upd_w1, M2, upd_w2, msg_w1, dec_w1, enc_w2, fG1, fG2, fPQ, fDec, fEnc);
    k_scatter<<<(NE + 255) / 256, 256, 0, stream>>>(srcp, tgtp, eattr, cnt, sea);
    k_enc<<<NN / 16, 512, 0, stream>>>(x, enc_w1, enc_b1, fEnc, enc_b2, fPQ, msg_b1, h_hi, h_lo, PQf0, Qb0);

    float* PQin = PQf0;
    u16* Qin = Qb0;
    float* PQout = PQf1;
    u16* Qout = Qb1;
    for (int l = 0; l < NL; ++l) {
        const float* wc = msg_w1 + (size_t)l * (2 * HD + EDIM) * HD + (size_t)2 * HD * HD;
        if (l < NL - 1) {
            k_layer<false><<<NN / 16, 512, 0, stream>>>(
                PQin, Qin, cnt, sea, wc, h_hi, h_lo,
                fG1 + (size_t)l * 32768, fG2 + (size_t)l * 16384,
                upd_b1 + l * HD, c2 + l * HD, upd_b2 + l * HD, ln_g + l * HD, ln_b + l * HD,
                fPQ + (size_t)(l + 1) * 32768, msg_b1 + (size_t)(l + 1) * HD, PQout, Qout,
                nullptr, nullptr, nullptr, nullptr, nullptr);
        } else {
            k_layer<true><<<NN / 16, 512, 0, stream>>>(
                PQin, Qin, cnt, sea, wc, h_hi, h_lo,
                fG1 + (size_t)l * 32768, fG2 + (size_t)l * 16384,
                upd_b1 + l * HD, c2 + l * HD, upd_b2 + l * HD, ln_g + l * HD, ln_b + l * HD,
                nullptr, nullptr, nullptr, nullptr,
                fDec, dec_b1, dec_w2, dec_b2, (float*)d_out);
        }
        float* tf = PQin; PQin = PQout; PQout = tf;
        u16* tq = Qin; Qin = Qout; Qout = tq;
    }
}

// Round 12
// 274.789 us; speedup vs baseline: 3.1776x; 1.0384x over previous
//
#include <hip/hip_runtime.h>

#define NN 10000
#define NE 400000
#define HD 128
#define NIN 6
#define EDIM 3
#define NL 4
#define CAP 96
#define LN_EPS 1e-5f

typedef unsigned short u16;
using short8 = __attribute__((ext_vector_type(8))) short;
using f32x4 = __attribute__((ext_vector_type(4))) float;

__device__ __forceinline__ u16 f2bf(float x) {
    unsigned u = __float_as_uint(x);
    return (u16)((u + 0x7fff + ((u >> 16) & 1)) >> 16);
}
__device__ __forceinline__ float bf2f(u16 h) { return __uint_as_float(((unsigned)h) << 16); }
__device__ __forceinline__ void split2(float x, u16& hi, u16& lo) {
    hi = f2bf(x);
    lo = f2bf(x - bf2f(hi));
}
#define MFMA(a, b, c) __builtin_amdgcn_mfma_f32_16x16x32_bf16((a), (b), (c), 0, 0, 0)

// ---- k_prepfrag: ALL weight prep in one kernel. M2 dots write DIRECTLY into fG1 fragment
// slots (no M2 buffer, no dependency on a prior kernel). idx ranges:
// [0,65536)       M2-dot (l,i,jj) -> fG1 hi-half element (k=128+i, n=jj)
// [65536,66048)   c2
// [66048,76048)   cnt zero
// [76048,84240)   fG1 lo-half (U1a rows, 8-elem groups)
// [84240,92432)   fG2 | [92432,108816) fPQ | [108816,110864) fDec | [110864,112912) fEnc

__global__ __launch_bounds__(256) void k_prepfrag(
    const float* __restrict__ msg_w2, const float* __restrict__ msg_b2, const float* __restrict__ upd_w1,
    const float* __restrict__ upd_w2, const float* __restrict__ msg_w1, const float* __restrict__ dec_w1,
    const float* __restrict__ enc_w2, float* __restrict__ c2, int* __restrict__ cnt,
    u16* __restrict__ fG1, u16* __restrict__ fG2, u16* __restrict__ fPQ,
    u16* __restrict__ fDec, u16* __restrict__ fEnc) {
    int idx = blockIdx.x * 256 + threadIdx.x;
    if (idx < 65536) {
        int l = idx >> 14, rem = idx & 16383, i = rem >> 7, jj = rem & 127;
        const float* U1b = upd_w1 + (size_t)l * 2 * HD * HD + (size_t)HD * HD;
        const float* W2 = msg_w2 + (size_t)l * HD * HD + (size_t)i * HD;
        float acc = 0.f;
        for (int t = 0; t < HD; ++t) acc += W2[t] * U1b[(size_t)t * HD + jj];
        // fragment slot for (l, k=128+i, n=jj)
        int ct = jj >> 4;
        int ks = 4 + (i >> 5);
        int lane = (((i & 31) >> 3) << 4) | (jj & 15);
        int j = i & 7;
        int g = (l << 12) | (ct << 9) | (ks << 6) | lane;
        fG1[(size_t)g * 8 + j] = f2bf(acc);
    } else if (idx < 66048) {
        int r = idx - 65536;
        int l = r >> 7, jj = r & 127;
        const float* U1b = upd_w1 + (size_t)l * 2 * HD * HD + (size_t)HD * HD;
        const float* b2 = msg_b2 + l * HD;
        float acc = 0.f;
        for (int t = 0; t < HD; ++t) acc += b2[t] * U1b[(size_t)t * HD + jj];
        c2[r] = acc;
    } else if (idx < 76048) {
        cnt[idx - 66048] = 0;
    } else if (idx < 84240) {
        int gl = idx - 76048;  // [0,8192): fG1 lo-half, ks in 0..3
        int l = gl >> 11, rem = gl & 2047;
        int ct = rem >> 8, ks = (rem >> 6) & 3, lane = rem & 63;
        int n = ct * 16 + (lane & 15), kb = ks * 32 + ((lane >> 4) << 3);
        int g = (l << 12) | (ct << 9) | (ks << 6) | lane;
        u16* dst = fG1 + (size_t)g * 8;
        const float* U = upd_w1 + (size_t)l * 256 * 128;
#pragma unroll
        for (int j = 0; j < 8; ++j) dst[j] = f2bf(U[(size_t)(kb + j) * 128 + n]);
    } else if (idx < 92432) {
        int gg = idx - 84240;
        int l = gg >> 11, r = gg & 2047;
        int ct = r >> 8, ks = (r >> 6) & 3, lane = r & 63;
        int n = ct * 16 + (lane & 15), kb = ks * 32 + ((lane >> 4) << 3);
        u16* dst = fG2 + (size_t)gg * 8;
        const float* W = upd_w2 + (size_t)l * 128 * 128;
#pragma unroll
        for (int j = 0; j < 8; ++j) dst[j] = f2bf(W[(size_t)(kb + j) * 128 + n]);
    } else if (idx < 108816) {
        int gg = idx - 92432;
        int li = gg >> 12, r = gg & 4095;
        int ct = r >> 8, ks = (r >> 6) & 3, lane = r & 63;
        int n = ct * 16 + (lane & 15), kb = ks * 32 + ((lane >> 4) << 3);
        u16* dst = fPQ + (size_t)gg * 8;
        const float* W = msg_w1 + (size_t)li * (2 * HD + EDIM) * HD;
#pragma unroll
        for (int j = 0; j < 8; ++j) {
            int k = kb + j;
            float v = (n < 128) ? W[(size_t)k * 128 + n] : W[(size_t)(128 + k) * 128 + (n - 128)];
            dst[j] = f2bf(v);
        }
    } else if (idx < 110864) {
        int r = idx - 108816;
        int ct = r >> 8, ks = (r >> 6) & 3, lane = r & 63;
        int n = ct * 16 + (lane & 15), kb = ks * 32 + ((lane >> 4) << 3);
        u16* dst = fDec + (size_t)r * 8;
#pragma unroll
        for (int j = 0; j < 8; ++j) dst[j] = f2bf(dec_w1[(size_t)(kb + j) * 128 + n]);
    } else if (idx < 112912) {
        int r = idx - 110864;
        int ct = r >> 8, ks = (r >> 6) & 3, lane = r & 63;
        int n = ct * 16 + (lane & 15), kb = ks * 32 + ((lane >> 4) << 3);
        u16* dst = fEnc + (size_t)r * 8;
#pragma unroll
        for (int j = 0; j < 8; ++j) dst[j] = f2bf(enc_w2[(size_t)(kb + j) * 128 + n]);
    }
}

// ---- k_scatenc: blocks [0,625) = encoder (16 nodes each); blocks [625,1407) = edge scatter ----

__global__ __launch_bounds__(512) void k_scatenc(
    const int* __restrict__ srcp, const int* __restrict__ tgtp, const float* __restrict__ eattr,
    int* __restrict__ cnt, float4* __restrict__ sea,
    const float* __restrict__ x, const float* __restrict__ ew1, const float* __restrict__ eb1,
    const u16* __restrict__ fEnc, const float* __restrict__ eb2, const u16* __restrict__ fPQ0,
    const float* __restrict__ mb1, u16* __restrict__ h_hi, u16* __restrict__ h_lo,
    float* __restrict__ PQf, u16* __restrict__ Qb) {
    __shared__ u16 tHi[2048], tLo[2048];
    if (blockIdx.x >= 625) {
        int e = (blockIdx.x - 625) * 512 + threadIdx.x;
        if (e < NE) {
            int t = tgtp[e];
            int pos = atomicAdd(&cnt[t], 1);
            if (pos < CAP) {
                sea[t * CAP + pos] = make_float4(eattr[e * 3], eattr[e * 3 + 1], eattr[e * 3 + 2],
                                                 __uint_as_float((unsigned)srcp[e]));
            }
        }
        return;
    }
    int tid = threadIdx.x, w = tid >> 6, lane = tid & 63, q = lane >> 4, c = lane & 15;
    int band = blockIdx.x * 16;
    // GEMM1: wave w covers cols [w*16, w*16+16)
    {
        int col = w * 16 + c;
        float wv[NIN];
#pragma unroll
        for (int k = 0; k < NIN; ++k) wv[k] = ew1[k * HD + col];
        float ebv = eb1[col];
#pragma unroll
        for (int reg = 0; reg < 4; ++reg) {
            int row = band + q * 4 + reg;
            float t = ebv;
#pragma unroll
            for (int k = 0; k < NIN; ++k) t += x[(size_t)row * NIN + k] * wv[k];
            t = fmaxf(t, 0.f);
            u16 hi, lo;
            split2(t, hi, lo);
            int r16 = q * 4 + reg;
            int a = r16 * 128 + (((col >> 3) ^ r16) << 3) + (col & 7);
            tHi[a] = hi;
            tLo[a] = lo;
        }
    }
    __syncthreads();
    short8 aH[4], aL[4];
#pragma unroll
    for (int ks = 0; ks < 4; ++ks) {
        int a = c * 128 + (((ks * 4 + q) ^ c) << 3);
        aH[ks] = *(const short8*)&tHi[a];
        aL[ks] = *(const short8*)&tLo[a];
    }
    // GEMM2: 1 ctg per wave
    f32x4 acc = {0, 0, 0, 0};
    {
        const u16* fb = fEnc + (size_t)w * 4 * 512 + lane * 8;
#pragma unroll
        for (int ks = 0; ks < 4; ++ks) {
            short8 b = *(const short8*)(fb + ks * 512);
            acc = MFMA(aH[ks], b, acc);
            acc = MFMA(aL[ks], b, acc);
        }
    }
    __syncthreads();
    {
        int col = w * 16 + c;
        float ebv = eb2[col];
#pragma unroll
        for (int reg = 0; reg < 4; ++reg) {
            int r16 = q * 4 + reg, row = band + r16;
            float hval = acc[reg] + ebv;
            u16 hi, lo;
            split2(hval, hi, lo);
            h_hi[(size_t)row * HD + col] = hi;
            h_lo[(size_t)row * HD + col] = lo;
            int a = r16 * 128 + (((col >> 3) ^ r16) << 3) + (col & 7);
            tHi[a] = hi;
            tLo[a] = lo;
        }
    }
    __syncthreads();
#pragma unroll
    for (int ks = 0; ks < 4; ++ks) {
        int a = c * 128 + (((ks * 4 + q) ^ c) << 3);
        aH[ks] = *(const short8*)&tHi[a];
        aL[ks] = *(const short8*)&tLo[a];
    }
    // PQ0: 2 ctg per wave
#pragma unroll
    for (int i = 0; i < 2; ++i) {
        int ctg = w * 2 + i;
        const u16* fb = fPQ0 + (size_t)ctg * 4 * 512 + lane * 8;
        f32x4 a3 = {0, 0, 0, 0};
#pragma unroll
        for (int ks = 0; ks < 4; ++ks) {
            short8 b = *(const short8*)(fb + ks * 512);
            a3 = MFMA(aH[ks], b, a3);
            a3 = MFMA(aL[ks], b, a3);
        }
        int col = ctg * 16 + c;
        if (ctg < 8) {
            float bias = mb1[col];
#pragma unroll
            for (int reg = 0; reg < 4; ++reg)
                PQf[(size_t)(band + q * 4 + reg) * HD + col] = a3[reg] + bias;
        } else {
            int colq = col - 128;
#pragma unroll
            for (int reg = 0; reg < 4; ++reg)
                Qb[(size_t)(band + q * 4 + reg) * HD + colq] = f2bf(a3[reg]);
        }
    }
}

// ------- fused layer (512 thr / 8 waves): edge-gather -> G1 -> G2 -> LN -> (PQ next | dec) -----

template <bool LAST>
__global__ __launch_bounds__(512) void k_layer(
    const float* __restrict__ PQf_in, const u16* __restrict__ Qb_in,
    const int* __restrict__ cnt, const float4* __restrict__ sea, const float* __restrict__ wc,
    u16* __restrict__ h_hi, u16* __restrict__ h_lo,
    const u16* __restrict__ fG1, const u16* __restrict__ fG2,
    const float* __restrict__ ub1, const float* __restrict__ c2l, const float* __restrict__ ub2,
    const float* __restrict__ g, const float* __restrict__ bb,
    const u16* __restrict__ fPQ, const float* __restrict__ nb1,
    float* __restrict__ PQf_out, u16* __restrict__ Qb_out,
    const u16* __restrict__ fDec, const float* __restrict__ db1, const float* __restrict__ dw2,
    const float* __restrict__ db2, float* __restrict__ out) {
    __shared__ u16 sHi[2048], sLo[2048];
    __shared__ u16 tHi[2048], tLo[2048];
    __shared__ float red[16][8][2];
    int tid = threadIdx.x, w = tid >> 6, lane = tid & 63, q = lane >> 4, c = lane & 15;
    int band = blockIdx.x * 16;
    int j = lane * 2;
    // ======== edge phase: wave w handles rows w*2, w*2+1 ========
    {
        float2 wcr0 = *(const float2*)(wc + j);
        float2 wcr1 = *(const float2*)(wc + HD + j);
        float2 wcr2 = *(const float2*)(wc + 2 * HD + j);
#pragma unroll
        for (int i = 0; i < 2; ++i) {
            int r16 = w * 2 + i;
            int n = __builtin_amdgcn_readfirstlane(band + r16);
            int cn = cnt[n];
            float invn = 1.0f / fmaxf((float)cn, 1.0f);
            int cle = __builtin_amdgcn_readfirstlane(cn < CAP ? cn : CAP);
            float2 p = *(const float2*)(PQf_in + (size_t)n * HD + j);
            float acc0 = 0.f, acc1 = 0.f;
            const float4* bucket = sea + (size_t)n * CAP;
            auto edge1 = [&](float4 A) {
                int sv = (int)__float_as_uint(A.w);
                float c0 = A.x * wcr0.x + A.y * wcr1.x + A.z * wcr2.x;
                float c1 = A.x * wcr0.y + A.y * wcr1.y + A.z * wcr2.y;
                unsigned u = *(const unsigned*)(Qb_in + (size_t)sv * HD + j);
                acc0 += fmaxf(p.x + __uint_as_float(u << 16) + c0, 0.f);
                acc1 += fmaxf(p.y + __uint_as_float(u & 0xffff0000u) + c1, 0.f);
            };
            int e = 0;
            for (; e + 3 < cle; e += 4) {
                float4 A0 = bucket[e], A1 = bucket[e + 1], A2 = bucket[e + 2], A3 = bucket[e + 3];
                edge1(A0);
                edge1(A1);
                edge1(A2);
                edge1(A3);
            }
            for (; e < cle; ++e) edge1(bucket[e]);
            float v0 = acc0 * invn, v1 = acc1 * invn;
            u16 h0, l0, h1, l1;
            split2(v0, h0, l0);
            split2(v1, h1, l1);
            int a = r16 * 128 + (((j >> 3) ^ r16) << 3) + (j & 7);
            *(ushort2*)&sHi[a] = make_ushort2(h0, h1);
            *(ushort2*)&sLo[a] = make_ushort2(l0, l1);
        }
    }
    __syncthreads();
    // ======== G1: A = [h (global) | S (LDS)], 1 ctg per wave ========
    short8 aH[8], aL[8];
    {
        size_t rb = (size_t)(band + c) * HD + q * 8;
#pragma unroll
        for (int ks = 0; ks < 4; ++ks) {
            aH[ks] = *(const short8*)(h_hi + rb + ks * 32);
            aL[ks] = *(const short8*)(h_lo + rb + ks * 32);
            int a = c * 128 + (((ks * 4 + q) ^ c) << 3);
            aH[4 + ks] = *(const short8*)&sHi[a];
            aL[4 + ks] = *(const short8*)&sLo[a];
        }
    }
    f32x4 acc = {0, 0, 0, 0};
    {
        const u16* fb = fG1 + (size_t)w * 8 * 512 + lane * 8;
#pragma unroll
        for (int ks = 0; ks < 8; ++ks) {
            short8 b = *(const short8*)(fb + ks * 512);
            acc = MFMA(aH[ks], b, acc);
            acc = MFMA(aL[ks], b, acc);
        }
    }
    float alv[4];
#pragma unroll
    for (int reg = 0; reg < 4; ++reg) alv[reg] = (cnt[band + q * 4 + reg] > 0) ? 1.f : 0.f;
    {
        int col = w * 16 + c;
        float u1b = ub1[col], cc = c2l[col];
#pragma unroll
        for (int reg = 0; reg < 4; ++reg) {
            int r16 = q * 4 + reg;
            float t = fmaxf(acc[reg] + u1b + alv[reg] * cc, 0.f);
            u16 hi, lo;
            split2(t, hi, lo);
            int a = r16 * 128 + (((col >> 3) ^ r16) << 3) + (col & 7);
            tHi[a] = hi;
            tLo[a] = lo;
        }
    }
    __syncthreads();
    // ======== G2: 1 ctg per wave ========
    short8 aH2[4], aL2[4];
#pragma unroll
    for (int ks = 0; ks < 4; ++ks) {
        int a = c * 128 + (((ks * 4 + q) ^ c) << 3);
        aH2[ks] = *(const short8*)&tHi[a];
        aL2[ks] = *(const short8*)&tLo[a];
    }
    f32x4 acc2 = {0, 0, 0, 0};
    {
        const u16* fb = fG2 + (size_t)w * 4 * 512 + lane * 8;
#pragma unroll
        for (int ks = 0; ks < 4; ++ks) {
            short8 b = *(const short8*)(fb + ks * 512);
            acc2 = MFMA(aH2[ks], b, acc2);
            acc2 = MFMA(aL2[ks], b, acc2);
        }
    }
    // ======== residual + LN ========
    float vv[4];
    {
        int col = w * 16 + c;
        float u2b = ub2[col];
#pragma unroll
        for (int reg = 0; reg < 4; ++reg) {
            size_t idx = (size_t)(band + q * 4 + reg) * HD + col;
            float hres = bf2f(h_hi[idx]) + bf2f(h_lo[idx]);
            vv[reg] = acc2[reg] + u2b + hres;
        }
    }
#pragma unroll
    for (int reg = 0; reg < 4; ++reg) {
        float s = vv[reg];
        float s2 = vv[reg] * vv[reg];
        for (int m = 1; m < 16; m <<= 1) {
            s += __shfl_xor(s, m);
            s2 += __shfl_xor(s2, m);
        }
        if (c == 0) {
            red[q * 4 + reg][w][0] = s;
            red[q * 4 + reg][w][1] = s2;
        }
    }
    __syncthreads();
    float mu[4], rs[4];
#pragma unroll
    for (int reg = 0; reg < 4; ++reg) {
        int r16 = q * 4 + reg;
        float S1 = 0.f, S2 = 0.f;
#pragma unroll
        for (int ww = 0; ww < 8; ++ww) {
            S1 += red[r16][ww][0];
            S2 += red[r16][ww][1];
        }
        float m = S1 * (1.f / HD);
        float var = S2 * (1.f / HD) - m * m;
        mu[reg] = m;
        rs[reg] = rsqrtf(var + LN_EPS);
    }
    {
        int col = w * 16 + c;
        float gg = g[col], bv = bb[col];
#pragma unroll
        for (int reg = 0; reg < 4; ++reg) {
            int r16 = q * 4 + reg;
            float o = (vv[reg] - mu[reg]) * rs[reg] * gg + bv;
            u16 hi, lo;
            split2(o, hi, lo);
            int a = r16 * 128 + (((col >> 3) ^ r16) << 3) + (col & 7);
            tHi[a] = hi;
            tLo[a] = lo;
            if (!LAST) {
                size_t idx = (size_t)(band + r16) * HD + col;
                h_hi[idx] = hi;
                h_lo[idx] = lo;
            }
        }
    }
    __syncthreads();
    short8 aH3[4], aL3[4];
#pragma unroll
    for (int ks = 0; ks < 4; ++ks) {
        int a = c * 128 + (((ks * 4 + q) ^ c) << 3);
        aH3[ks] = *(const short8*)&tHi[a];
        aL3[ks] = *(const short8*)&tLo[a];
    }
    if (!LAST) {
        // PQ(next): 2 ctg per wave
#pragma unroll
        for (int i = 0; i < 2; ++i) {
            int ctg = w * 2 + i;
            const u16* fb = fPQ + (size_t)ctg * 4 * 512 + lane * 8;
            f32x4 a3 = {0, 0, 0, 0};
#pragma unroll
            for (int ks = 0; ks < 4; ++ks) {
                short8 b = *(const short8*)(fb + ks * 512);
                a3 = MFMA(aH3[ks], b, a3);
                a3 = MFMA(aL3[ks], b, a3);
            }
            int col = ctg * 16 + c;
            if (ctg < 8) {
                float bias = nb1[col];
#pragma unroll
                for (int reg = 0; reg < 4; ++reg)
                    PQf_out[(size_t)(band + q * 4 + reg) * HD + col] = a3[reg] + bias;
            } else {
                int colq = col - 128;
#pragma unroll
                for (int reg = 0; reg < 4; ++reg)
                    Qb_out[(size_t)(band + q * 4 + reg) * HD + colq] = f2bf(a3[reg]);
            }
        }
    } else {
        // decoder: 1 ctg per wave
        float part[4];
        {
            const u16* fb = fDec + (size_t)w * 4 * 512 + lane * 8;
            f32x4 a3 = {0, 0, 0, 0};
#pragma unroll
            for (int ks = 0; ks < 4; ++ks) {
                short8 b = *(const short8*)(fb + ks * 512);
                a3 = MFMA(aH3[ks], b, a3);
                a3 = MFMA(aL3[ks], b, a3);
            }
            int col = w * 16 + c;
            float w2v = dw2[col], b1v = db1[col];
#pragma unroll
            for (int reg = 0; reg < 4; ++reg) part[reg] = fmaxf(a3[reg] + b1v, 0.f) * w2v;
        }
#pragma unroll
        for (int reg = 0; reg < 4; ++reg) {
            float s = part[reg];
            for (int m = 1; m < 16; m <<= 1) s += __shfl_xor(s, m);
            if (c == 0) red[q * 4 + reg][w][0] = s;
        }
        __syncthreads();
        if (tid < 16) {
            float s = db2[0];
#pragma unroll
            for (int ww = 0; ww < 8; ++ww) s += red[tid][ww][0];
            out[band + tid] = s;
        }
    }
}

// ---------------- launch ----------------

extern "C" void kernel_launch(void* const* d_in, const int* in_sizes, int n_in,
                              void* d_out, int out_size, void* d_ws, size_t ws_size,
                              hipStream_t stream) {
    const float* x = (const float*)d_in[0];
    const int* eidx = (const int*)d_in[1];
    const float* eattr = (const float*)d_in[2];
    const float* enc_w1 = (const float*)d_in[3];
    const float* enc_b1 = (const float*)d_in[4];
    const float* enc_w2 = (const float*)d_in[5];
    const float* enc_b2 = (const float*)d_in[6];
    const float* msg_w1 = (const float*)d_in[7];
    const float* msg_b1 = (const float*)d_in[8];
    const float* msg_w2 = (const float*)d_in[9];
    const float* msg_b2 = (const float*)d_in[10];
    const float* upd_w1 = (const float*)d_in[11];
    const float* upd_b1 = (const float*)d_in[12];
    const float* upd_w2 = (const float*)d_in[13];
    const float* upd_b2 = (const float*)d_in[14];
    const float* ln_g = (const float*)d_in[15];
    const float* ln_b = (const float*)d_in[16];
    const float* dec_w1 = (const float*)d_in[17];
    const float* dec_b1 = (const float*)d_in[18];
    const float* dec_w2 = (const float*)d_in[19];
    const float* dec_b2 = (const float*)d_in[20];
    const int* srcp = eidx;
    const int* tgtp = eidx + NE;

    char* base = (char*)d_ws;
    size_t off = 0;
    auto alloc = [&](size_t bytes) -> void* {
        off = (off + 15) & ~(size_t)15;
        void* p = base + off;
        off += bytes;
        return p;
    };
    float4* sea = (float4*)alloc((size_t)NN * CAP * 16);
    float* PQf0 = (float*)alloc((size_t)NN * HD * 4);
    float* PQf1 = (float*)alloc((size_t)NN * HD * 4);
    u16* Qb0 = (u16*)alloc((size_t)NN * HD * 2);
    u16* Qb1 = (u16*)alloc((size_t)NN * HD * 2);
    u16* h_hi = (u16*)alloc((size_t)NN * HD * 2);
    u16* h_lo = (u16*)alloc((size_t)NN * HD * 2);
    int* cnt = (int*)alloc((size_t)NN * 4);
    float* c2 = (float*)alloc((size_t)NL * HD * 4);
    u16* fG1 = (u16*)alloc((size_t)131072 * 2);
    u16* fG2 = (u16*)alloc((size_t)65536 * 2);
    u16* fPQ = (u16*)alloc((size_t)131072 * 2);
    u16* fDec = (u16*)alloc((size_t)16384 * 2);
    u16* fEnc = (u16*)alloc((size_t)16384 * 2);

    k_prepfrag<<<442, 256, 0, stream>>>(msg_w2, msg_b2, upd_w1, upd_w2, msg_w1, dec_w1, enc_w2,
                                        c2, cnt, fG1, fG2, fPQ, fDec, fEnc);
    k_scatenc<<<625 + (NE + 511) / 512, 512, 0, stream>>>(srcp, tgtp, eattr, cnt, sea,
                                                          x, enc_w1, enc_b1, fEnc, enc_b2, fPQ,
                                                          msg_b1, h_hi, h_lo, PQf0, Qb0);

    float* PQin = PQf0;
    u16* Qin = Qb0;
    float* PQout = PQf1;
    u16* Qout = Qb1;
    for (int l = 0; l < NL; ++l) {
        const float* wc = msg_w1 + (size_t)l * (2 * HD + EDIM) * HD + (size_t)2 * HD * HD;
        if (l < NL - 1) {
            k_layer<false><<<NN / 16, 512, 0, stream>>>(
                PQin, Qin, cnt, sea, wc, h_hi, h_lo,
                fG1 + (size_t)l * 32768, fG2 + (size_t)l * 16384,
                upd_b1 + l * HD, c2 + l * HD, upd_b2 + l * HD, ln_g + l * HD, ln_b + l * HD,
                fPQ + (size_t)(l + 1) * 32768, msg_b1 + (size_t)(l + 1) * HD, PQout, Qout,
                nullptr, nullptr, nullptr, nullptr, nullptr);
        } else {
            k_layer<true><<<NN / 16, 512, 0, stream>>>(
                PQin, Qin, cnt, sea, wc, h_hi, h_lo,
                fG1 + (size_t)l * 32768, fG2 + (size_t)l * 16384,
                upd_b1 + l * HD, c2 + l * HD, upd_b2 + l * HD, ln_g + l * HD, ln_b + l * HD,
                nullptr, nullptr, nullptr, nullptr,
                fDec, dec_b1, dec_w2, dec_b2, (float*)d_out);
        }
        float* tf = PQin; PQin = PQout; PQout = tf;
        u16* tq = Qin; Qin = Qout; Qout = tq;
    }
}